// Round 7
// baseline (208.286 us; speedup 1.0000x reference)
//
#include <hip/hip_runtime.h>
#include <math.h>

#define NCH 12500        // 12500 chunks x 64 rows = 800000
#define GRID 256
#define BLK 1024
#define NWAVE 4096       // GRID * 16 waves

typedef __attribute__((ext_vector_type(8))) short short8;
typedef __attribute__((ext_vector_type(4))) float f32x4;
typedef float f4a __attribute__((ext_vector_type(4), aligned(4)));

// ---- LDS layout (bytes) ----
#define W2T_OFF 0        // 16384  [c=128][k=64] bf16 swz
#define W3T_OFF 16384    // 24576  [c=96][k=128] bf16 swz
#define WIT_OFF 40960    //  4608  [c=96][k=24]  bf16 linear (48B rows)
#define B2_OFF  45568    //   512  f32[128]
#define BC_OFF  46080    //   384  f32[96]
#define W1I_OFF 46464    //  1024  float4[64] = (W1[0][k], W1[1][k], b1[k], 0)
#define WV_OFF  47488    // 16 waves x 7168
#define H2S 0            //  4096  [16][128] bf16 swz
#define ANB 4096         //  3072  [64][24]  bf16 linear (48B rows)
#define WV_SZ 7168
#define LDS_TOT (WV_OFF + 16 * WV_SZ)   // 162176 <= 163840

__device__ __forceinline__ float sis(float t) {
    t = fminf(fmaxf(t, 0.01f), 0.99f);
    return logf(t / (1.0f - t));
}
__device__ __forceinline__ unsigned short f2bf(float f) {
    unsigned int u = __float_as_uint(f);
    return (unsigned short)((u + 0x7FFFu + ((u >> 16) & 1u)) >> 16);
}
__device__ __forceinline__ unsigned int cvtpk(float a, float b) {
    unsigned int r;
    asm("v_cvt_pk_bf16_f32 %0, %1, %2" : "=v"(r) : "v"(a), "v"(b));
    return r;
}
union S8 { uint4 q; short8 v; };

__global__ __launch_bounds__(BLK, 4) void k_main(
    const float* __restrict__ gp,
    const float* __restrict__ zbuf,
    const float* __restrict__ w2c,
    const float* __restrict__ ck,
    const float* __restrict__ vo,
    const float* __restrict__ ss,
    const float* __restrict__ cvr,
    const float* __restrict__ W1, const float* __restrict__ b1,
    const float* __restrict__ W2, const float* __restrict__ b2,
    const float* __restrict__ W3, const float* __restrict__ b3,
    const float* __restrict__ Wi, const float* __restrict__ bi,
    float* __restrict__ oA, float* __restrict__ oT,
    float* __restrict__ oI, float* __restrict__ oP, float* __restrict__ oM,
    int* __restrict__ ctr, int usews)
{
    __shared__ __align__(16) char lds[LDS_TOT];
    float* sB2 = (float*)(lds + B2_OFF);
    float* sBC = (float*)(lds + BC_OFF);
    const float4* sW1 = (const float4*)(lds + W1I_OFF);

    const int t   = threadIdx.x;
    const int wv  = t >> 6;
    const int l   = t & 63;
    const int la  = l & 15;
    const int lb  = l >> 4;
    char* wlds = lds + WV_OFF + wv * WV_SZ;

    // ---- build shared weight images ----
    for (int idx = t; idx < 8192; idx += BLK) {            // W2T
        int k = idx >> 7, c = idx & 127;
        *(unsigned short*)(lds + W2T_OFF + c*128 + (((k>>3) ^ (c&7))<<4) + (k&7)*2)
            = f2bf(W2[idx]);
    }
    for (int idx = t; idx < 12288; idx += BLK) {           // W3T
        int k = idx / 96, c = idx - k*96;
        *(unsigned short*)(lds + W3T_OFF + c*256 + (((k>>3) ^ (c&15))<<4) + (k&7)*2)
            = f2bf(W3[idx]);
    }
    for (int idx = t; idx < 2304; idx += BLK) {            // WIT [c][k<24]
        int c = idx / 24, k = idx - c*24;
        *(unsigned short*)(lds + WIT_OFF + c*48 + k*2) = f2bf(Wi[k*96 + c]);
    }
    if (t < 128) sB2[t] = b2[t];
    if (t < 96)  sBC[t] = b3[t] + bi[t];
    if (t < 64)  ((float4*)(lds + W1I_OFF))[t] = make_float4(W1[t], W1[64+t], b1[t], 0.f);

    // uniforms
    const float R00=w2c[0],R01=w2c[1],R02=w2c[2],T0=w2c[3];
    const float R10=w2c[4],R11=w2c[5],R12=w2c[6],T1=w2c[7];
    const float R20=w2c[8],R21=w2c[9],R22=w2c[10],T2=w2c[11];
    const float k00=ck[0],k02=ck[2],k11=ck[4],k12=ck[5];
    const float n0=vo[0]+1e-3f, n1=vo[1]+1e-3f, n2=vo[2]+1e-3f;
    const float f0=vo[0]+ss[0]-1e-3f, f1=vo[1]+ss[1]-1e-3f, f2=vo[2]+ss[2]-1e-3f;
    const float cv0=cvr[0],cv1=cvr[1],cv2=cvr[2],cv3=cvr[3],cv4=cvr[4],cv5=cvr[5];
    const float i30=1.0f/(cv3-cv0), i41=1.0f/(cv4-cv1), i52=1.0f/(cv5-cv2);
    const float qtr = R00 + R11 + R22;
    const float qw = sqrtf(fmaxf(qtr + 1.0f, 1e-8f)) * 0.5f;
    const float qi4 = 0.25f / qw;
    const float qx = (R21-R12)*qi4, qy=(R02-R20)*qi4, qz=(R10-R01)*qi4;

    __syncthreads();   // only block-wide barrier

    int n = blockIdx.x * 16 + wv;   // first chunk static
    while (n < NCH) {
        const long Rb = (long)n * 64;
        const long R  = Rb + l;

        // ---- row load: 6 vec4 + 1 scalar (4B-aligned vec ok) ----
        const float* g = gp + R * 25;
        f4a q0 = *(const f4a*)(g);
        f4a q1 = *(const f4a*)(g + 4);
        f4a q2v= *(const f4a*)(g + 8);
        f4a q3 = *(const f4a*)(g + 12);
        f4a q4 = *(const f4a*)(g + 16);
        f4a q5 = *(const f4a*)(g + 20);
        float v24 = g[24];

        // ---- geometry ----
        const float x=q0.x, y=q0.y, zz=q0.z;
        const float c0 = R00*x + R01*y + R02*zz + T0;
        const float c1 = R10*x + R11*y + R12*zz + T1;
        const float c2 = R20*x + R21*y + R22*zz + T2;

        bool m1 = c2 > 1e-6f;
        float zc = m1 ? c2 : 1e-6f;
        float fpx = k00 * c0 / zc + k02;
        float fpy = k11 * c1 / zc + k12;
        bool m2 = (fpx >= 0.f) && (fpx < 640.f) && (fpy >= 0.f) && (fpy < 480.f);
        bool mall = m1 && m2;
        bool gpm = (x>n0)&&(x<f0)&&(y>n1)&&(y<f1)&&(zz>n2)&&(zz<f2);
        bool mdet = mall && gpm;
        float tag = (q5.w == 1.0f) ? 0.5f : 0.0f;
        if (!mdet) tag = 1.0f;
        bool gm = (c0>=cv0)&&(c0<=cv3)&&(c1>=cv1)&&(c1<=cv4)&&(c2>=cv2)&&(c2<=cv5);
        bool reuse = gpm && gm;
        float mkf = reuse ? 1.0f : 0.0f;

        oM[R] = mkf;
        oT[R] = reuse ? tag : 0.0f;

        // oP: vec stores + patched col 24
        {
            float* pr = oP + R * 25;
            *(f4a*)(pr)      = q0;
            *(f4a*)(pr + 4)  = q1;
            *(f4a*)(pr + 8)  = q2v;
            *(f4a*)(pr + 12) = q3;
            *(f4a*)(pr + 16) = q4;
            *(f4a*)(pr + 20) = q5;
            pr[24] = gpm ? 1.0f : v24;
        }

        // df
        float czs = (fabsf(c2) < 1e-6f) ? 1e-6f : c2;
        float px = k00*c0/czs + k02;
        float py = k11*c1/czs + k12;
        int ix = (int)fminf(fmaxf(px, 0.f), 639.f);
        int iy = (int)fminf(fmaxf(py, 0.f), 479.f);
        float d0 = zbuf[iy*640 + ix];
        float d1 = c2;

        // anchor
        float a0,a1v,a2,a3,a4,a5,a6,a7,a8,a9,a10;
        float a11,a12,a13,a14,a15,a16,a17,a18,a19,a20,a21,a22;
        if (reuse) {
            float p0=q1.z, p1=q1.w, p2=q2v.x, p3=q2v.y;
            a0 = sis((c0 - cv0) * i30);
            a1v= sis((c1 - cv1) * i41);
            a2 = sis((c2 - cv2) * i52);
            a3 = sis(q0.w); a4 = sis(q1.x); a5 = sis(q1.y);
            a6 = qw*p0 - qx*p1 - qy*p2 - qz*p3;
            a7 = qw*p1 + qx*p0 + qy*p3 - qz*p2;
            a8 = qw*p2 - qx*p3 + qy*p0 + qz*p1;
            a9 = qw*p3 + qx*p2 - qy*p1 + qz*p0;
            a10 = sis(q2v.z);
            a11=q2v.w; a12=q3.x; a13=q3.y; a14=q3.z; a15=q3.w;
            a16=q4.x; a17=q4.y; a18=q4.z; a19=q4.w;
            a20=q5.x; a21=q5.y; a22=q5.z;
        } else {
            a0=a1v=a2=a3=a4=a5=a6=a7=a8=a9=a10=0.f;
            a11=a12=a13=a14=a15=a16=a17=a18=a19=a20=a21=a22=0.f;
        }

        // oA: 6 vec stores (last overlaps at 19)
        {
            float* aro = oA + R * 23;
            f4a s0 = {a0,a1v,a2,a3};   *(f4a*)(aro)      = s0;
            f4a s1 = {a4,a5,a6,a7};    *(f4a*)(aro + 4)  = s1;
            f4a s2 = {a8,a9,a10,a11};  *(f4a*)(aro + 8)  = s2;
            f4a s3 = {a12,a13,a14,a15};*(f4a*)(aro + 12) = s3;
            f4a s4 = {a16,a17,a18,a19};*(f4a*)(aro + 16) = s4;
            f4a s5 = {a19,a20,a21,a22};*(f4a*)(aro + 19) = s5;
        }

        // AN image: row l, 24 bf16 (k=23 zero), 48B rows
        {
            char* anr = wlds + ANB + l*48;
            uint4 u0, u1, u2;
            u0.x=cvtpk(a0,a1v); u0.y=cvtpk(a2,a3);  u0.z=cvtpk(a4,a5);   u0.w=cvtpk(a6,a7);
            u1.x=cvtpk(a8,a9);  u1.y=cvtpk(a10,a11);u1.z=cvtpk(a12,a13); u1.w=cvtpk(a14,a15);
            u2.x=cvtpk(a16,a17);u2.y=cvtpk(a18,a19);u2.z=cvtpk(a20,a21); u2.w=cvtpk(a22,0.f);
            *(uint4*)(anr)      = u0;
            *(uint4*)(anr + 16) = u1;
            *(uint4*)(anr + 32) = u2;
        }

        // ---- 4 strips of 16 rows ----
        for (int s = 0; s < 4; ++s) {
            const int rsrc = 16*s + la;
            float d0s = __shfl(d0, rsrc);
            float d1s = __shfl(d1, rsrc);
            float mks = __shfl(mkf, rsrc);

            // h1 in-lane: k = lb*8+j and 32+lb*8+j
            S8 hb0u, hb1u;
            {
                const int kb = lb * 8;
                float h[8], h2[8];
                #pragma unroll
                for (int j = 0; j < 8; ++j) {
                    float4 w = sW1[kb + j];
                    h[j] = fmaxf(fmaf(d0s, w.x, fmaf(d1s, w.y, w.z)), 0.f);
                }
                #pragma unroll
                for (int j = 0; j < 8; ++j) {
                    float4 w = sW1[32 + kb + j];
                    h2[j] = fmaxf(fmaf(d0s, w.x, fmaf(d1s, w.y, w.z)), 0.f);
                }
                hb0u.q.x = cvtpk(h[0],h[1]);  hb0u.q.y = cvtpk(h[2],h[3]);
                hb0u.q.z = cvtpk(h[4],h[5]);  hb0u.q.w = cvtpk(h[6],h[7]);
                hb1u.q.x = cvtpk(h2[0],h2[1]);hb1u.q.y = cvtpk(h2[2],h2[3]);
                hb1u.q.z = cvtpk(h2[4],h2[5]);hb1u.q.w = cvtpk(h2[6],h2[7]);
            }

            // GEMM1: H2 strip
            {
                #pragma unroll
                for (int ct = 0; ct < 8; ++ct) {
                    const int cc = ct*16 + la;
                    short8 w0 = *(short8*)(lds + W2T_OFF + cc*128 + (((lb  ) ^ (cc&7))<<4));
                    short8 w1v= *(short8*)(lds + W2T_OFF + cc*128 + (((lb+4) ^ (cc&7))<<4));
                    f32x4 acc = {0.f, 0.f, 0.f, 0.f};
                    acc = __builtin_amdgcn_mfma_f32_16x16x32_bf16(w0, hb0u.v, acc, 0, 0, 0);
                    acc = __builtin_amdgcn_mfma_f32_16x16x32_bf16(w1v, hb1u.v, acc, 0, 0, 0);
                    float4 bb = *(float4*)&sB2[ct*16 + lb*4];
                    float e0 = fmaxf(acc[0] + bb.x, 0.f);
                    float e1 = fmaxf(acc[1] + bb.y, 0.f);
                    float e2 = fmaxf(acc[2] + bb.z, 0.f);
                    float e3 = fmaxf(acc[3] + bb.w, 0.f);
                    uint2 pk; pk.x = cvtpk(e0, e1); pk.y = cvtpk(e2, e3);
                    const int gg = ct*2 + (lb>>1);
                    *(uint2*)(wlds + H2S + la*256 + ((gg ^ la)<<4) + (lb&1)*8) = pk;
                }
            }

            // GEMM2
            {
                short8 B0 = *(short8*)(wlds + H2S + la*256 + ((( 0 + lb) ^ la)<<4));
                short8 B1 = *(short8*)(wlds + H2S + la*256 + ((( 4 + lb) ^ la)<<4));
                short8 B2v= *(short8*)(wlds + H2S + la*256 + ((( 8 + lb) ^ la)<<4));
                short8 B3 = *(short8*)(wlds + H2S + la*256 + (((12 + lb) ^ la)<<4));
                short8 bA;
                if (lb < 3) bA = *(short8*)(wlds + ANB + rsrc*48 + lb*16);
                else { S8 z; z.q = make_uint4(0,0,0,0); bA = z.v; }
                float* orow = oI + (Rb + rsrc) * 96;
                #pragma unroll
                for (int ct = 0; ct < 6; ++ct) {
                    const int cc = ct*16 + la;
                    f32x4 acc = {0.f, 0.f, 0.f, 0.f};
                    short8 A0 = *(short8*)(lds + W3T_OFF + cc*256 + ((( 0 + lb) ^ (cc&15))<<4));
                    short8 A1 = *(short8*)(lds + W3T_OFF + cc*256 + ((( 4 + lb) ^ (cc&15))<<4));
                    short8 A2 = *(short8*)(lds + W3T_OFF + cc*256 + ((( 8 + lb) ^ (cc&15))<<4));
                    short8 A3 = *(short8*)(lds + W3T_OFF + cc*256 + (((12 + lb) ^ (cc&15))<<4));
                    acc = __builtin_amdgcn_mfma_f32_16x16x32_bf16(A0, B0, acc, 0, 0, 0);
                    acc = __builtin_amdgcn_mfma_f32_16x16x32_bf16(A1, B1, acc, 0, 0, 0);
                    acc = __builtin_amdgcn_mfma_f32_16x16x32_bf16(A2, B2v, acc, 0, 0, 0);
                    acc = __builtin_amdgcn_mfma_f32_16x16x32_bf16(A3, B3, acc, 0, 0, 0);
                    short8 Aw;
                    if (lb < 3) Aw = *(short8*)(lds + WIT_OFF + cc*48 + lb*16);
                    else { S8 z; z.q = make_uint4(0,0,0,0); Aw = z.v; }
                    acc = __builtin_amdgcn_mfma_f32_16x16x32_bf16(Aw, bA, acc, 0, 0, 0);
                    float4 bb = *(float4*)&sBC[ct*16 + lb*4];
                    float4 o;
                    o.x = (mks != 0.f) ? acc[0] + bb.x : 0.f;
                    o.y = (mks != 0.f) ? acc[1] + bb.y : 0.f;
                    o.z = (mks != 0.f) ? acc[2] + bb.z : 0.f;
                    o.w = (mks != 0.f) ? acc[3] + bb.w : 0.f;
                    *(float4*)(orow + ct*16 + lb*4) = o;
                }
            }
        }

        // next chunk: work-stealing (deterministic output; chunks disjoint)
        if (usews) {
            int nn;
            if (l == 0) nn = atomicAdd(ctr, 1);
            n = NWAVE + __shfl(nn, 0);
        } else {
            n += NWAVE;
        }
    }
}

extern "C" void kernel_launch(void* const* d_in, const int* in_sizes, int n_in,
                              void* d_out, int out_size, void* d_ws, size_t ws_size,
                              hipStream_t stream)
{
    const float* gp  = (const float*)d_in[0];
    const float* zb  = (const float*)d_in[2];
    const float* w2c = (const float*)d_in[3];
    const float* ck  = (const float*)d_in[4];
    const float* vo  = (const float*)d_in[5];
    const float* ss  = (const float*)d_in[6];
    const float* cvr = (const float*)d_in[7];
    const float* Wi  = (const float*)d_in[8];
    const float* bi  = (const float*)d_in[9];
    const float* W1  = (const float*)d_in[10];
    const float* b1  = (const float*)d_in[11];
    const float* W2  = (const float*)d_in[12];
    const float* b2  = (const float*)d_in[13];
    const float* W3  = (const float*)d_in[14];
    const float* b3  = (const float*)d_in[15];

    float* out = (float*)d_out;
    const long N = 800000;
    float* oA = out;               // (N,23)
    float* oT = out + 23L * N;     // (N,)
    float* oI = out + 24L * N;     // (N,96)
    float* oP = out + 120L * N;    // (N,25)
    float* oM = out + 145L * N;    // (N,)

    int usews = (ws_size >= 4) ? 1 : 0;
    int* ctr = (int*)d_ws;
    if (usews) hipMemsetAsync(d_ws, 0, 4, stream);

    k_main<<<GRID, BLK, 0, stream>>>(gp, zb, w2c, ck, vo, ss, cvr,
                                     W1, b1, W2, b2, W3, b3, Wi, bi,
                                     oA, oT, oI, oP, oM, ctr, usews);
}